// Round 11
// baseline (211.346 us; speedup 1.0000x reference)
//
#include <hip/hip_runtime.h>

typedef float f16v __attribute__((ext_vector_type(16)));
typedef float f4 __attribute__((ext_vector_type(4)));
typedef float f2 __attribute__((ext_vector_type(2)));

// static_for with FRONTEND-constant indices (SSA, no alloca) — see R6 notes.
template<int I> struct ic { static constexpr int v = I; };
template<int... I> struct iseq {};
template<int N, int... I> struct mk : mk<N-1, N-1, I...> {};
template<int... I> struct mk<0, I...> { using t = iseq<I...>; };
template<class F, int... I>
__device__ __forceinline__ void sfor_impl(F f, iseq<I...>) { (f(ic<I>{}), ...); }
template<int N, class F>
__device__ __forceinline__ void sfor(F f) { sfor_impl(f, typename mk<N>::t{}); }

namespace {
constexpr float kSigma  = 1.2f;    // 2*l2_reg + rho
constexpr float kJitter = 1e-5f;
constexpr int   kIters  = 100;
constexpr int   MD = 16;
constexpr int   ND = 32;
constexpr int   SPA  = 8;    // samples per 128-thread precompute block (16 lanes each)
constexpr int   SPB2 = 16;   // samples per 256-thread iter block (16 lanes each)
constexpr int   SPB  = 8;    // fallback kernel
constexpr int   AS  = 132;
constexpr int   SS  = 36;
constexpr int   MIS = 20;
constexpr int   MSS = 328;
}

__device__ __forceinline__ float4 lds_a4(const float* As, int r, int j) {
    return *reinterpret_cast<const float4*>(&As[r * 32 + ((j ^ (r & 7)) << 2)]);
}
__device__ __forceinline__ float lds_a(const float* As, int r, int n) {
    return As[r * 32 + ((((n >> 2) ^ (r & 7)) << 2) | (n & 3))];
}
__device__ __forceinline__ f2 lds_a2(const float* As, int r, int n) {
    return *reinterpret_cast<const f2*>(
        &As[r * 32 + ((((n >> 2) ^ (r & 7)) << 2) | (n & 3))]);
}

// ============================ Kernel A: precompute P, d ============================
// Lane l owns M row l and P rows 2l,2l+1. P stored per sample as 16 f4 slots:
//   Pws[gs*1024] f4[cp*16 + l] = (P[2l][2cp], P[2l+1][2cp], P[2l][2cp+1], P[2l+1][2cp+1])
// (column-pair-major fragments; natural cp order — iter kernel permutes at load).
__global__ void __launch_bounds__(128)
precompute_kernel(const float* __restrict__ Ag, const float* __restrict__ bg,
                  const float* __restrict__ cg, float* __restrict__ Pws,
                  float* __restrict__ dws)
{
    __shared__ __align__(16) float A_lds[SPA * AS * 4];
    __shared__ __align__(16) float Mi_lds[SPA * MSS];

    const int t = threadIdx.x;

    {
        const float4* src = reinterpret_cast<const float4*>(Ag) +
                            (size_t)blockIdx.x * (SPA * MD * ND / 4);
        float4* dst = reinterpret_cast<float4*>(A_lds);
        #pragma unroll
        for (int r = 0; r < 8; ++r) {
            int idx = r * 128 + t;
            int smp = idx >> 7;
            int row = (idx >> 3) & 15;
            int j   = idx & 7;
            dst[smp * AS + row * 8 + (j ^ (row & 7))] = src[idx];
        }
    }
    __syncthreads();

    const int lane = t & 63;
    const int l    = lane & 15;
    const int n0   = 2 * l;
    const int smp  = (t >> 6) * 4 + (lane >> 4);
    const size_t gs = (size_t)blockIdx.x * SPA + smp;
    const float* As = &A_lds[smp * AS * 4];
    float* Mi = &Mi_lds[smp * MSS];

    f16v Ar0, Ar1;
    sfor<4>([&](auto J) {
        constexpr int j = decltype(J)::v;
        float4 v  = lds_a4(As, l, j);
        Ar0[4*j+0] = v.x;  Ar0[4*j+1] = v.y;  Ar0[4*j+2] = v.z;  Ar0[4*j+3] = v.w;
        float4 w4 = lds_a4(As, l, j + 4);
        Ar1[4*j+0] = w4.x; Ar1[4*j+1] = w4.y; Ar1[4*j+2] = w4.z; Ar1[4*j+3] = w4.w;
    });

    f16v Mrow, Vrow;
    sfor<16>([&](auto K) {
        constexpr int k = decltype(K)::v;
        float a0 = 0.f, a1 = 0.f, a2 = 0.f, a3 = 0.f;
        sfor<4>([&](auto J) {
            constexpr int j = decltype(J)::v;
            float4 v  = lds_a4(As, k, j);
            a0 += Ar0[4*j+0]*v.x;  a1 += Ar0[4*j+1]*v.y;
            a2 += Ar0[4*j+2]*v.z;  a3 += Ar0[4*j+3]*v.w;
            float4 w4 = lds_a4(As, k, j + 4);
            a0 += Ar1[4*j+0]*w4.x; a1 += Ar1[4*j+1]*w4.y;
            a2 += Ar1[4*j+2]*w4.z; a3 += Ar1[4*j+3]*w4.w;
        });
        Mrow[k] = (a0+a1)+(a2+a3) + ((k == l) ? kJitter : 0.f);
        Vrow[k] = (k == l) ? 1.f : 0.f;
    });

    sfor<16>([&](auto K) {
        constexpr int k = decltype(K)::v;
        float ip = 1.f / __shfl(Mrow[k], k, 16);
        float f  = (l == k) ? 0.f : Mrow[k] * ip;
        sfor<16>([&](auto J) {
            constexpr int j = decltype(J)::v;
            if constexpr (j > k) {
                float mj = __shfl(Mrow[j], k, 16);
                Mrow[j] = (l == k) ? mj * ip : Mrow[j] - f * mj;
            }
        });
        sfor<16>([&](auto J) {
            constexpr int j = decltype(J)::v;
            if constexpr (j < k) {
                float vj = __shfl(Vrow[j], k, 16);
                Vrow[j] = (l == k) ? vj * ip : Vrow[j] - f * vj;
            }
        });
        Vrow[k] = (l == k) ? ip : -f;
    });

    float w = 0.f;
    {
        float bval = bg[gs * MD + l];
        sfor<16>([&](auto K) {
            constexpr int k = decltype(K)::v;
            w += Vrow[k] * __shfl(bval, k, 16);
        });
    }

    sfor<4>([&](auto J) {
        constexpr int j = decltype(J)::v;
        *reinterpret_cast<float4*>(&Mi[l * MIS + 4*j]) =
            make_float4(Vrow[4*j+0], Vrow[4*j+1], Vrow[4*j+2], Vrow[4*j+3]);
    });
    asm volatile("s_waitcnt lgkmcnt(0)" ::: "memory");

    f16v Ca = (f16v)0.0f, Cb = (f16v)0.0f;
    float q0 = 0.f, q1 = 0.f;
    sfor<16>([&](auto K) {
        constexpr int k = decltype(K)::v;
        f2 ak = lds_a2(As, k, n0);
        float wm = __shfl(w, k, 16);
        q0 += ak[0] * wm;
        q1 += ak[1] * wm;
        sfor<4>([&](auto J) {
            constexpr int j = decltype(J)::v;
            float4 mv = *reinterpret_cast<const float4*>(&Mi[k * MIS + 4*j]);
            Ca[4*j+0] += ak[0]*mv.x; Ca[4*j+1] += ak[0]*mv.y;
            Ca[4*j+2] += ak[0]*mv.z; Ca[4*j+3] += ak[0]*mv.w;
            Cb[4*j+0] += ak[1]*mv.x; Cb[4*j+1] += ak[1]*mv.y;
            Cb[4*j+2] += ak[1]*mv.z; Cb[4*j+3] += ak[1]*mv.w;
        });
    });

    f16v P0a = (f16v)0.0f, P0b = (f16v)0.0f;
    f16v P1a = (f16v)0.0f, P1b = (f16v)0.0f;
    sfor<16>([&](auto M) {
        constexpr int m = decltype(M)::v;
        float c0 = Ca[m], c1 = Cb[m];
        sfor<4>([&](auto J) {
            constexpr int j = decltype(J)::v;
            float4 v  = lds_a4(As, m, j);
            P0a[4*j+0] += c0*v.x;  P0a[4*j+1] += c0*v.y;
            P0a[4*j+2] += c0*v.z;  P0a[4*j+3] += c0*v.w;
            P1a[4*j+0] += c1*v.x;  P1a[4*j+1] += c1*v.y;
            P1a[4*j+2] += c1*v.z;  P1a[4*j+3] += c1*v.w;
            float4 w4 = lds_a4(As, m, j + 4);
            P0b[4*j+0] += c0*w4.x; P0b[4*j+1] += c0*w4.y;
            P0b[4*j+2] += c0*w4.z; P0b[4*j+3] += c0*w4.w;
            P1b[4*j+0] += c1*w4.x; P1b[4*j+1] += c1*w4.y;
            P1b[4*j+2] += c1*w4.z; P1b[4*j+3] += c1*w4.w;
        });
    });
    constexpr float is = 1.f / kSigma;
    sfor<16>([&](auto N) {
        constexpr int n = decltype(N)::v;
        P0a[n] = (((n      == n0    ) ? 1.f : 0.f) - P0a[n]) * is;
        P0b[n] = (((n + 16 == n0    ) ? 1.f : 0.f) - P0b[n]) * is;
        P1a[n] = (((n      == n0 + 1) ? 1.f : 0.f) - P1a[n]) * is;
        P1b[n] = (((n + 16 == n0 + 1) ? 1.f : 0.f) - P1b[n]) * is;
    });

    float d0, d1;
    {
        float cv0 = cg[gs * ND + l];
        float cv1 = cg[gs * ND + 16 + l];
        float pc0 = 0.f, pc1 = 0.f;
        sfor<16>([&](auto N) {
            constexpr int n = decltype(N)::v;
            float cn = __shfl(cv0, n, 16);
            pc0 += P0a[n] * cn;
            pc1 += P1a[n] * cn;
        });
        sfor<16>([&](auto N) {
            constexpr int n = decltype(N)::v;
            float cn = __shfl(cv1, n, 16);
            pc0 += P0b[n] * cn;
            pc1 += P1b[n] * cn;
        });
        d0 = q0 - pc0;
        d1 = q1 - pc1;
    }

    {
        float4* Pout = reinterpret_cast<float4*>(Pws + gs * (ND * ND));
        sfor<8>([&](auto N) {
            constexpr int n = decltype(N)::v;
            // col-pair-major fragment: (r0 cLo, r1 cLo, r0 cHi, r1 cHi)
            Pout[n * 16 + l]       = make_float4(P0a[2*n], P1a[2*n], P0a[2*n+1], P1a[2*n+1]);
            Pout[(n + 8) * 16 + l] = make_float4(P0b[2*n], P1b[2*n], P0b[2*n+1], P1b[2*n+1]);
        });
        f2 dd; dd[0] = d0; dd[1] = d1;
        *reinterpret_cast<f2*>(dws + gs * ND + 2 * l) = dd;
    }
}

// ============================ Kernel B: 100 ADMM iterations ============================
// ZERO LDS. s-pair lives in registers; the all-to-all P·s is a 16-step DPP ring:
// step r uses v_mov_dpp row_ror:r (VALU pipe) to fetch lane (l-r)&15's s-pair, and a
// P fragment pre-permuted at load (cp=(l-r)&15). Eliminates the 8KB/wave-iter LDS
// return traffic that bounded R10's iter kernel at ~112us.
#define ROTR(x, ctrl) __int_as_float(__builtin_amdgcn_update_dpp( \
        __float_as_int(x), __float_as_int(x), (ctrl), 0xf, 0xf, false))

__global__ void __launch_bounds__(256)
admm_iter_kernel(const float* __restrict__ Pws, const float* __restrict__ dws,
                 const float* __restrict__ lbg, const float* __restrict__ ubg,
                 float* __restrict__ outg)
{
    const int t = threadIdx.x;
    const int lane = t & 63;
    const int l = lane & 15;                       // lane within 16-lane ring
    const int smp = (t >> 6) * 4 + (lane >> 4);
    const size_t gs = (size_t)blockIdx.x * SPB2 + smp;

    // q##r = P fragment for step r: columns 2cp,2cp+1 with cp=(l-r)&15, rows 2l,2l+1.
    const f4* Pw = reinterpret_cast<const f4*>(Pws + gs * (ND * ND));
#define PL(r) f4 q##r = Pw[(((l - (r)) & 15) << 4) + l];
    PL(0)  PL(1)  PL(2)  PL(3)  PL(4)  PL(5)  PL(6)  PL(7)
    PL(8)  PL(9)  PL(10) PL(11) PL(12) PL(13) PL(14) PL(15)
#undef PL

    f2 dv = *reinterpret_cast<const f2*>(dws + gs * ND + 2 * l);
    f2 lb = *reinterpret_cast<const f2*>(lbg + gs * ND + 2 * l);
    f2 ub = *reinterpret_cast<const f2*>(ubg + gs * ND + 2 * l);
    f2 z  = __builtin_elementwise_min(__builtin_elementwise_max((f2)0.0f, lb), ub);
    f2 u  = (f2)0.0f;
    f2 x  = (f2)0.0f;

    for (int it = 0; it < kIters; ++it) {
        f2 sp = z - u;                       // own s-pair (rho == 1); no LDS write
        f2 acc0 = dv;
        f2 acc1 = (f2)0.0f;
        // step 0: cp = l, s-pair is local
        acc0 = __builtin_elementwise_fma(__builtin_shufflevector(q0, q0, 0, 1),
                                         __builtin_shufflevector(sp, sp, 0, 0), acc0);
        acc1 = __builtin_elementwise_fma(__builtin_shufflevector(q0, q0, 2, 3),
                                         __builtin_shufflevector(sp, sp, 1, 1), acc1);
#define STEP(r)  {                                                             \
        f2 sr; sr[0] = ROTR(sp[0], 0x120 + (r));                               \
        sr[1] = ROTR(sp[1], 0x120 + (r));                                      \
        acc0 = __builtin_elementwise_fma(__builtin_shufflevector(q##r, q##r, 0, 1), \
                                         __builtin_shufflevector(sr, sr, 0, 0), acc0); \
        acc1 = __builtin_elementwise_fma(__builtin_shufflevector(q##r, q##r, 2, 3), \
                                         __builtin_shufflevector(sr, sr, 1, 1), acc1); }
        STEP(1)  STEP(2)  STEP(3)  STEP(4)  STEP(5)  STEP(6)  STEP(7)
        STEP(8)  STEP(9)  STEP(10) STEP(11) STEP(12) STEP(13) STEP(14) STEP(15)
#undef STEP
        x = acc0 + acc1;
        f2 tv = x + u;
        z = __builtin_elementwise_min(__builtin_elementwise_max(tv, lb), ub);
        u = tv - z;
    }

    *reinterpret_cast<f2*>(outg + gs * ND + 2 * l) = x;
}

// ==================== Fallback: single kernel (if ws too small) ====================
__global__ void __launch_bounds__(256)
admm_qp_kernel(const float* __restrict__ Ag, const float* __restrict__ bg,
               const float* __restrict__ cg, const float* __restrict__ lbg,
               const float* __restrict__ ubg, float* __restrict__ outg)
{
    __shared__ __align__(16) float A_lds[SPB * AS * 4];
    __shared__ __align__(16) float S_lds[SPB * SS];

    const int t = threadIdx.x;
    {
        const float4* src = reinterpret_cast<const float4*>(Ag) +
                            (size_t)blockIdx.x * (SPB * MD * ND / 4);
        float4* dst = reinterpret_cast<float4*>(A_lds);
        #pragma unroll
        for (int r = 0; r < 4; ++r) {
            int idx = r * 256 + t;
            int smp = idx >> 7;
            int row = (idx >> 3) & 15;
            int j   = idx & 7;
            dst[smp * AS + row * 8 + (j ^ (row & 7))] = src[idx];
        }
    }
    __syncthreads();

    const int lane = t & 63;
    const int l    = lane & 31;
    const int lr   = l & 15;
    const int smp  = (t >> 6) * 2 + (lane >> 5);
    const size_t gs = (size_t)blockIdx.x * SPB + smp;
    const float* As = &A_lds[smp * AS * 4];
    float* Sb = &S_lds[smp * SS];

    f16v Mrow, Vrow;
    sfor<16>([&](auto K) {
        constexpr int k = decltype(K)::v;
        float a0 = 0.f, a1 = 0.f, a2 = 0.f, a3 = 0.f;
        sfor<8>([&](auto J) {
            constexpr int j = decltype(J)::v;
            float4 va = lds_a4(As, lr, j);
            float4 vb = lds_a4(As, k, j);
            a0 += va.x*vb.x; a1 += va.y*vb.y; a2 += va.z*vb.z; a3 += va.w*vb.w;
        });
        Mrow[k] = (a0+a1)+(a2+a3) + ((k == lr) ? kJitter : 0.f);
        Vrow[k] = (k == lr) ? 1.f : 0.f;
    });
    sfor<16>([&](auto K) {
        constexpr int k = decltype(K)::v;
        float ip = 1.f / __shfl(Mrow[k], k, 32);
        float f  = (lr == k) ? 0.f : Mrow[k] * ip;
        sfor<16>([&](auto J) {
            constexpr int j = decltype(J)::v;
            if constexpr (j > k) {
                float mj = __shfl(Mrow[j], k, 32);
                Mrow[j] = (lr == k) ? mj * ip : Mrow[j] - f * mj;
            }
        });
        sfor<16>([&](auto J) {
            constexpr int j = decltype(J)::v;
            if constexpr (j < k) {
                float vj = __shfl(Vrow[j], k, 32);
                Vrow[j] = (lr == k) ? vj * ip : Vrow[j] - f * vj;
            }
        });
        Vrow[k] = (lr == k) ? ip : -f;
    });
    float w = 0.f;
    {
        float bval = bg[gs * MD + lr];
        sfor<16>([&](auto K) {
            constexpr int k = decltype(K)::v;
            w += Vrow[k] * __shfl(bval, k, 32);
        });
    }
    f16v C = (f16v)0.0f;
    sfor<16>([&](auto K) {
        constexpr int k = decltype(K)::v;
        float a = lds_a(As, k, l);
        sfor<16>([&](auto M) {
            constexpr int m = decltype(M)::v;
            C[m] += a * __shfl(Vrow[m], k, 32);
        });
    });
    f16v Pa = (f16v)0.0f, Pb = (f16v)0.0f;
    sfor<16>([&](auto M) {
        constexpr int m = decltype(M)::v;
        float cm = C[m];
        sfor<4>([&](auto J) {
            constexpr int j = decltype(J)::v;
            float4 v  = lds_a4(As, m, j);
            Pa[4*j+0] += cm*v.x;  Pa[4*j+1] += cm*v.y;
            Pa[4*j+2] += cm*v.z;  Pa[4*j+3] += cm*v.w;
            float4 w4 = lds_a4(As, m, j + 4);
            Pb[4*j+0] += cm*w4.x; Pb[4*j+1] += cm*w4.y;
            Pb[4*j+2] += cm*w4.z; Pb[4*j+3] += cm*w4.w;
        });
    });
    constexpr float is = 1.f / kSigma;
    sfor<16>([&](auto N) {
        constexpr int n = decltype(N)::v;
        Pa[n] = (((n      == l) ? 1.f : 0.f) - Pa[n]) * is;
        Pb[n] = (((n + 16 == l) ? 1.f : 0.f) - Pb[n]) * is;
    });
    float d;
    {
        float q = 0.f;
        sfor<16>([&](auto M) {
            constexpr int m = decltype(M)::v;
            q += lds_a(As, m, l) * __shfl(w, m, 32);
        });
        float cval = cg[gs * ND + l];
        float pc0 = 0.f, pc1 = 0.f;
        sfor<16>([&](auto N) {
            constexpr int n = decltype(N)::v;
            pc0 += Pa[n] * __shfl(cval, n,      32);
            pc1 += Pb[n] * __shfl(cval, n + 16, 32);
        });
        d = q - (pc0 + pc1);
    }
    float lb = lbg[gs * ND + l];
    float ub = ubg[gs * ND + l];
    float z  = fminf(fmaxf(0.f, lb), ub);
    float u  = 0.f, x = 0.f;
    for (int it = 0; it < kIters; ++it) {
        Sb[l] = z - u;
        asm volatile("s_waitcnt lgkmcnt(0)" ::: "memory");
        float a0 = d, a1 = 0.f, a2 = 0.f, a3 = 0.f;
        sfor<4>([&](auto K) {
            constexpr int k = decltype(K)::v;
            float4 sA = *reinterpret_cast<const float4*>(&Sb[4*k]);
            float4 sB = *reinterpret_cast<const float4*>(&Sb[4*k + 16]);
            a0 += Pa[4*k+0]*sA.x + Pb[4*k+0]*sB.x;
            a1 += Pa[4*k+1]*sA.y + Pb[4*k+1]*sB.y;
            a2 += Pa[4*k+2]*sA.z + Pb[4*k+2]*sB.z;
            a3 += Pa[4*k+3]*sA.w + Pb[4*k+3]*sB.w;
        });
        x = (a0 + a1) + (a2 + a3);
        float tv = x + u;
        z = fminf(fmaxf(tv, lb), ub);
        u = tv - z;
    }
    outg[gs * ND + l] = x;
}

extern "C" void kernel_launch(void* const* d_in, const int* in_sizes, int n_in,
                              void* d_out, int out_size, void* d_ws, size_t ws_size,
                              hipStream_t stream) {
    const float* A  = (const float*)d_in[0];
    const float* b  = (const float*)d_in[1];
    const float* c  = (const float*)d_in[2];
    const float* lb = (const float*)d_in[3];
    const float* ub = (const float*)d_in[4];
    float* out = (float*)d_out;
    const int B = in_sizes[1] / MD;                       // 32768 samples
    const size_t needP = (size_t)B * ND * ND * sizeof(float);   // 128 MiB
    const size_t needD = (size_t)B * ND * sizeof(float);        // 4 MiB
    if (ws_size >= needP + needD) {
        float* Pws = (float*)d_ws;
        float* dws = Pws + (size_t)B * ND * ND;
        precompute_kernel<<<B / SPA, 128, 0, stream>>>(A, b, c, Pws, dws);
        admm_iter_kernel<<<B / SPB2, 256, 0, stream>>>(Pws, dws, lb, ub, out);
    } else {
        admm_qp_kernel<<<B / SPB, 256, 0, stream>>>(A, b, c, lb, ub, out);
    }
}

// Round 12
// 181.315 us; speedup vs baseline: 1.1656x; 1.1656x over previous
//
#include <hip/hip_runtime.h>

typedef float f16v __attribute__((ext_vector_type(16)));
typedef float f4 __attribute__((ext_vector_type(4)));
typedef float f2 __attribute__((ext_vector_type(2)));

// static_for with FRONTEND-constant indices (SSA, no alloca) — see R6 notes.
template<int I> struct ic { static constexpr int v = I; };
template<int... I> struct iseq {};
template<int N, int... I> struct mk : mk<N-1, N-1, I...> {};
template<int... I> struct mk<0, I...> { using t = iseq<I...>; };
template<class F, int... I>
__device__ __forceinline__ void sfor_impl(F f, iseq<I...>) { (f(ic<I>{}), ...); }
template<int N, class F>
__device__ __forceinline__ void sfor(F f) { sfor_impl(f, typename mk<N>::t{}); }

// Guaranteed packed fp32 FMA: d = a*b + d (elementwise on f2).
__device__ __forceinline__ void pk_fma(f2& d, f2 a, f2 b) {
    asm("v_pk_fma_f32 %0, %1, %2, %0" : "+v"(d) : "v"(a), "v"(b));
}

namespace {
constexpr float kSigma  = 1.2f;    // 2*l2_reg + rho
constexpr float kJitter = 1e-5f;
constexpr int   kIters  = 100;
constexpr int   MD = 16;
constexpr int   ND = 32;
constexpr int   SPA  = 8;    // samples per 128-thread precompute block (16 lanes each)
constexpr int   SPB3 = 32;   // samples per 256-thread iter block (8 lanes each)
constexpr int   SPB  = 8;    // fallback kernel
constexpr int   AS  = 132;
constexpr int   SS  = 36;    // s-slot stride: 36%32==4 -> 8 groups cover all 32 banks
constexpr int   MIS = 20;
constexpr int   MSS = 328;
}

__device__ __forceinline__ float4 lds_a4(const float* As, int r, int j) {
    return *reinterpret_cast<const float4*>(&As[r * 32 + ((j ^ (r & 7)) << 2)]);
}
__device__ __forceinline__ float lds_a(const float* As, int r, int n) {
    return As[r * 32 + ((((n >> 2) ^ (r & 7)) << 2) | (n & 3))];
}
__device__ __forceinline__ f2 lds_a2(const float* As, int r, int n) {
    return *reinterpret_cast<const f2*>(
        &As[r * 32 + ((((n >> 2) ^ (r & 7)) << 2) | (n & 3))]);
}

// ============================ Kernel A: precompute P, d ============================
// Lane l owns P rows 2l, 2l+1. Store layout for the 8-lane iter kernel:
//   f4 slot [j*8 + base], base = (l&1)*128 + l/2, j=0..15 covering cols (2j,2j+1):
//   (P[ra][2j], P[ra][2j+1], P[rb][2j], P[rb][2j+1]) with (ra,rb)=(2l,2l+1).
// Iter lane l3 reads qa_j = slot[j*8+l3] (rows 4l3,4l3+1), qb_j = slot[128+j*8+l3].
__global__ void __launch_bounds__(128)
precompute_kernel(const float* __restrict__ Ag, const float* __restrict__ bg,
                  const float* __restrict__ cg, float* __restrict__ Pws,
                  float* __restrict__ dws)
{
    __shared__ __align__(16) float A_lds[SPA * AS * 4];
    __shared__ __align__(16) float Mi_lds[SPA * MSS];

    const int t = threadIdx.x;

    {
        const float4* src = reinterpret_cast<const float4*>(Ag) +
                            (size_t)blockIdx.x * (SPA * MD * ND / 4);
        float4* dst = reinterpret_cast<float4*>(A_lds);
        #pragma unroll
        for (int r = 0; r < 8; ++r) {
            int idx = r * 128 + t;
            int smp = idx >> 7;
            int row = (idx >> 3) & 15;
            int j   = idx & 7;
            dst[smp * AS + row * 8 + (j ^ (row & 7))] = src[idx];
        }
    }
    __syncthreads();

    const int lane = t & 63;
    const int l    = lane & 15;
    const int n0   = 2 * l;
    const int smp  = (t >> 6) * 4 + (lane >> 4);
    const size_t gs = (size_t)blockIdx.x * SPA + smp;
    const float* As = &A_lds[smp * AS * 4];
    float* Mi = &Mi_lds[smp * MSS];

    f16v Ar0, Ar1;
    sfor<4>([&](auto J) {
        constexpr int j = decltype(J)::v;
        float4 v  = lds_a4(As, l, j);
        Ar0[4*j+0] = v.x;  Ar0[4*j+1] = v.y;  Ar0[4*j+2] = v.z;  Ar0[4*j+3] = v.w;
        float4 w4 = lds_a4(As, l, j + 4);
        Ar1[4*j+0] = w4.x; Ar1[4*j+1] = w4.y; Ar1[4*j+2] = w4.z; Ar1[4*j+3] = w4.w;
    });

    f16v Mrow, Vrow;
    sfor<16>([&](auto K) {
        constexpr int k = decltype(K)::v;
        float a0 = 0.f, a1 = 0.f, a2 = 0.f, a3 = 0.f;
        sfor<4>([&](auto J) {
            constexpr int j = decltype(J)::v;
            float4 v  = lds_a4(As, k, j);
            a0 += Ar0[4*j+0]*v.x;  a1 += Ar0[4*j+1]*v.y;
            a2 += Ar0[4*j+2]*v.z;  a3 += Ar0[4*j+3]*v.w;
            float4 w4 = lds_a4(As, k, j + 4);
            a0 += Ar1[4*j+0]*w4.x; a1 += Ar1[4*j+1]*w4.y;
            a2 += Ar1[4*j+2]*w4.z; a3 += Ar1[4*j+3]*w4.w;
        });
        Mrow[k] = (a0+a1)+(a2+a3) + ((k == l) ? kJitter : 0.f);
        Vrow[k] = (k == l) ? 1.f : 0.f;
    });

    sfor<16>([&](auto K) {
        constexpr int k = decltype(K)::v;
        float ip = 1.f / __shfl(Mrow[k], k, 16);
        float f  = (l == k) ? 0.f : Mrow[k] * ip;
        sfor<16>([&](auto J) {
            constexpr int j = decltype(J)::v;
            if constexpr (j > k) {
                float mj = __shfl(Mrow[j], k, 16);
                Mrow[j] = (l == k) ? mj * ip : Mrow[j] - f * mj;
            }
        });
        sfor<16>([&](auto J) {
            constexpr int j = decltype(J)::v;
            if constexpr (j < k) {
                float vj = __shfl(Vrow[j], k, 16);
                Vrow[j] = (l == k) ? vj * ip : Vrow[j] - f * vj;
            }
        });
        Vrow[k] = (l == k) ? ip : -f;
    });

    float w = 0.f;
    {
        float bval = bg[gs * MD + l];
        sfor<16>([&](auto K) {
            constexpr int k = decltype(K)::v;
            w += Vrow[k] * __shfl(bval, k, 16);
        });
    }

    sfor<4>([&](auto J) {
        constexpr int j = decltype(J)::v;
        *reinterpret_cast<float4*>(&Mi[l * MIS + 4*j]) =
            make_float4(Vrow[4*j+0], Vrow[4*j+1], Vrow[4*j+2], Vrow[4*j+3]);
    });
    asm volatile("s_waitcnt lgkmcnt(0)" ::: "memory");

    f16v Ca = (f16v)0.0f, Cb = (f16v)0.0f;
    float q0 = 0.f, q1 = 0.f;
    sfor<16>([&](auto K) {
        constexpr int k = decltype(K)::v;
        f2 ak = lds_a2(As, k, n0);
        float wm = __shfl(w, k, 16);
        q0 += ak[0] * wm;
        q1 += ak[1] * wm;
        sfor<4>([&](auto J) {
            constexpr int j = decltype(J)::v;
            float4 mv = *reinterpret_cast<const float4*>(&Mi[k * MIS + 4*j]);
            Ca[4*j+0] += ak[0]*mv.x; Ca[4*j+1] += ak[0]*mv.y;
            Ca[4*j+2] += ak[0]*mv.z; Ca[4*j+3] += ak[0]*mv.w;
            Cb[4*j+0] += ak[1]*mv.x; Cb[4*j+1] += ak[1]*mv.y;
            Cb[4*j+2] += ak[1]*mv.z; Cb[4*j+3] += ak[1]*mv.w;
        });
    });

    f16v P0a = (f16v)0.0f, P0b = (f16v)0.0f;
    f16v P1a = (f16v)0.0f, P1b = (f16v)0.0f;
    sfor<16>([&](auto M) {
        constexpr int m = decltype(M)::v;
        float c0 = Ca[m], c1 = Cb[m];
        sfor<4>([&](auto J) {
            constexpr int j = decltype(J)::v;
            float4 v  = lds_a4(As, m, j);
            P0a[4*j+0] += c0*v.x;  P0a[4*j+1] += c0*v.y;
            P0a[4*j+2] += c0*v.z;  P0a[4*j+3] += c0*v.w;
            P1a[4*j+0] += c1*v.x;  P1a[4*j+1] += c1*v.y;
            P1a[4*j+2] += c1*v.z;  P1a[4*j+3] += c1*v.w;
            float4 w4 = lds_a4(As, m, j + 4);
            P0b[4*j+0] += c0*w4.x; P0b[4*j+1] += c0*w4.y;
            P0b[4*j+2] += c0*w4.z; P0b[4*j+3] += c0*w4.w;
            P1b[4*j+0] += c1*w4.x; P1b[4*j+1] += c1*w4.y;
            P1b[4*j+2] += c1*w4.z; P1b[4*j+3] += c1*w4.w;
        });
    });
    constexpr float is = 1.f / kSigma;
    sfor<16>([&](auto N) {
        constexpr int n = decltype(N)::v;
        P0a[n] = (((n      == n0    ) ? 1.f : 0.f) - P0a[n]) * is;
        P0b[n] = (((n + 16 == n0    ) ? 1.f : 0.f) - P0b[n]) * is;
        P1a[n] = (((n      == n0 + 1) ? 1.f : 0.f) - P1a[n]) * is;
        P1b[n] = (((n + 16 == n0 + 1) ? 1.f : 0.f) - P1b[n]) * is;
    });

    float d0, d1;
    {
        float cv0 = cg[gs * ND + l];
        float cv1 = cg[gs * ND + 16 + l];
        float pc0 = 0.f, pc1 = 0.f;
        sfor<16>([&](auto N) {
            constexpr int n = decltype(N)::v;
            float cn = __shfl(cv0, n, 16);
            pc0 += P0a[n] * cn;
            pc1 += P1a[n] * cn;
        });
        sfor<16>([&](auto N) {
            constexpr int n = decltype(N)::v;
            float cn = __shfl(cv1, n, 16);
            pc0 += P0b[n] * cn;
            pc1 += P1b[n] * cn;
        });
        d0 = q0 - pc0;
        d1 = q1 - pc1;
    }

    {
        float4* Pout = reinterpret_cast<float4*>(Pws + gs * (ND * ND));
        const int base = ((l & 1) << 7) + (l >> 1);   // odd row-pairs -> +128 f4
        sfor<8>([&](auto N) {
            constexpr int n = decltype(N)::v;
            Pout[n * 8 + base]       = make_float4(P0a[2*n], P0a[2*n+1], P1a[2*n], P1a[2*n+1]);
            Pout[(n + 8) * 8 + base] = make_float4(P0b[2*n], P0b[2*n+1], P1b[2*n], P1b[2*n+1]);
        });
        f2 dd; dd[0] = d0; dd[1] = d1;
        *reinterpret_cast<f2*>(dws + gs * ND + 2 * l) = dd;
    }
}

// ============================ Kernel B: 100 ADMM iterations ============================
// 8 lanes/sample, 4 rows/lane. Accumulators are (even-col, odd-col) f2 partials:
//   acc_r += (P[r][2j], P[r][2j+1]) (*) (s[2j], s[2j+1])   -- pure elementwise
// v_pk_fma_f32 via inline asm (64/iter, NO splat shuffles -- R9/R11's hidden cost).
// s exchange: 1 ds_write_b128 + 8 uniform ds_read_b128 serving 8 samples/wave;
// stride-36 slots put the 8 groups' reads on all 32 banks exactly once.
__global__ void __launch_bounds__(256)
admm_iter_kernel(const float* __restrict__ Pws, const float* __restrict__ dws,
                 const float* __restrict__ lbg, const float* __restrict__ ubg,
                 float* __restrict__ outg)
{
    __shared__ __align__(16) float S_lds[SPB3 * SS];   // 4608 B

    const int t = threadIdx.x;
    const int lane = t & 63;
    const int l3 = lane & 7;                       // lane within 8-lane group
    const int smp = (t >> 6) * 8 + (lane >> 3);    // sample within block
    const size_t gs = (size_t)blockIdx.x * SPB3 + smp;
    float* Sb = &S_lds[smp * SS];

    const f4* Pw = reinterpret_cast<const f4*>(Pws + gs * (ND * ND));
#define PL(j) f4 qa##j = Pw[(j) * 8 + l3]; f4 qb##j = Pw[128 + (j) * 8 + l3];
    PL(0)  PL(1)  PL(2)  PL(3)  PL(4)  PL(5)  PL(6)  PL(7)
    PL(8)  PL(9)  PL(10) PL(11) PL(12) PL(13) PL(14) PL(15)
#undef PL

    f4 dv = *reinterpret_cast<const f4*>(dws + gs * ND + 4 * l3);
    f4 lb = *reinterpret_cast<const f4*>(lbg + gs * ND + 4 * l3);
    f4 ub = *reinterpret_cast<const f4*>(ubg + gs * ND + 4 * l3);
    f4 z  = __builtin_elementwise_min(__builtin_elementwise_max((f4)0.0f, lb), ub);
    f4 u  = (f4)0.0f;
    f4 xv = (f4)0.0f;

    const f4* Sv = reinterpret_cast<const f4*>(Sb);
    for (int it = 0; it < kIters; ++it) {
        *reinterpret_cast<f4*>(&Sb[4 * l3]) = z - u;       // rho == 1
        asm volatile("s_waitcnt lgkmcnt(0)" ::: "memory"); // wave-synchronous exchange
        f2 acc0, acc1, acc2, acc3;
        acc0[0] = dv[0]; acc0[1] = 0.f;
        acc1[0] = dv[1]; acc1[1] = 0.f;
        acc2[0] = dv[2]; acc2[1] = 0.f;
        acc3[0] = dv[3]; acc3[1] = 0.f;
#define STEP(k, jA, jB) {                                                     \
        f4 S4 = Sv[k];                        /* s[4k..4k+3], uniform/group */\
        f2 sA = __builtin_shufflevector(S4, S4, 0, 1);                        \
        f2 sB = __builtin_shufflevector(S4, S4, 2, 3);                        \
        pk_fma(acc0, __builtin_shufflevector(qa##jA, qa##jA, 0, 1), sA);      \
        pk_fma(acc1, __builtin_shufflevector(qa##jA, qa##jA, 2, 3), sA);      \
        pk_fma(acc2, __builtin_shufflevector(qb##jA, qb##jA, 0, 1), sA);      \
        pk_fma(acc3, __builtin_shufflevector(qb##jA, qb##jA, 2, 3), sA);      \
        pk_fma(acc0, __builtin_shufflevector(qa##jB, qa##jB, 0, 1), sB);      \
        pk_fma(acc1, __builtin_shufflevector(qa##jB, qa##jB, 2, 3), sB);      \
        pk_fma(acc2, __builtin_shufflevector(qb##jB, qb##jB, 0, 1), sB);      \
        pk_fma(acc3, __builtin_shufflevector(qb##jB, qb##jB, 2, 3), sB); }
        STEP(0, 0,  1)  STEP(1, 2,  3)  STEP(2, 4,  5)  STEP(3, 6,  7)
        STEP(4, 8,  9)  STEP(5, 10, 11) STEP(6, 12, 13) STEP(7, 14, 15)
#undef STEP
        xv[0] = acc0[0] + acc0[1];
        xv[1] = acc1[0] + acc1[1];
        xv[2] = acc2[0] + acc2[1];
        xv[3] = acc3[0] + acc3[1];
        f4 tv = xv + u;
        z = __builtin_elementwise_min(__builtin_elementwise_max(tv, lb), ub);
        u = tv - z;
    }

    *reinterpret_cast<f4*>(outg + gs * ND + 4 * l3) = xv;
}

// ==================== Fallback: single kernel (if ws too small) ====================
__global__ void __launch_bounds__(256)
admm_qp_kernel(const float* __restrict__ Ag, const float* __restrict__ bg,
               const float* __restrict__ cg, const float* __restrict__ lbg,
               const float* __restrict__ ubg, float* __restrict__ outg)
{
    __shared__ __align__(16) float A_lds[SPB * AS * 4];
    __shared__ __align__(16) float S_lds[SPB * SS];

    const int t = threadIdx.x;
    {
        const float4* src = reinterpret_cast<const float4*>(Ag) +
                            (size_t)blockIdx.x * (SPB * MD * ND / 4);
        float4* dst = reinterpret_cast<float4*>(A_lds);
        #pragma unroll
        for (int r = 0; r < 4; ++r) {
            int idx = r * 256 + t;
            int smp = idx >> 7;
            int row = (idx >> 3) & 15;
            int j   = idx & 7;
            dst[smp * AS + row * 8 + (j ^ (row & 7))] = src[idx];
        }
    }
    __syncthreads();

    const int lane = t & 63;
    const int l    = lane & 31;
    const int lr   = l & 15;
    const int smp  = (t >> 6) * 2 + (lane >> 5);
    const size_t gs = (size_t)blockIdx.x * SPB + smp;
    const float* As = &A_lds[smp * AS * 4];
    float* Sb = &S_lds[smp * SS];

    f16v Mrow, Vrow;
    sfor<16>([&](auto K) {
        constexpr int k = decltype(K)::v;
        float a0 = 0.f, a1 = 0.f, a2 = 0.f, a3 = 0.f;
        sfor<8>([&](auto J) {
            constexpr int j = decltype(J)::v;
            float4 va = lds_a4(As, lr, j);
            float4 vb = lds_a4(As, k, j);
            a0 += va.x*vb.x; a1 += va.y*vb.y; a2 += va.z*vb.z; a3 += va.w*vb.w;
        });
        Mrow[k] = (a0+a1)+(a2+a3) + ((k == lr) ? kJitter : 0.f);
        Vrow[k] = (k == lr) ? 1.f : 0.f;
    });
    sfor<16>([&](auto K) {
        constexpr int k = decltype(K)::v;
        float ip = 1.f / __shfl(Mrow[k], k, 32);
        float f  = (lr == k) ? 0.f : Mrow[k] * ip;
        sfor<16>([&](auto J) {
            constexpr int j = decltype(J)::v;
            if constexpr (j > k) {
                float mj = __shfl(Mrow[j], k, 32);
                Mrow[j] = (lr == k) ? mj * ip : Mrow[j] - f * mj;
            }
        });
        sfor<16>([&](auto J) {
            constexpr int j = decltype(J)::v;
            if constexpr (j < k) {
                float vj = __shfl(Vrow[j], k, 32);
                Vrow[j] = (lr == k) ? vj * ip : Vrow[j] - f * vj;
            }
        });
        Vrow[k] = (lr == k) ? ip : -f;
    });
    float w = 0.f;
    {
        float bval = bg[gs * MD + lr];
        sfor<16>([&](auto K) {
            constexpr int k = decltype(K)::v;
            w += Vrow[k] * __shfl(bval, k, 32);
        });
    }
    f16v C = (f16v)0.0f;
    sfor<16>([&](auto K) {
        constexpr int k = decltype(K)::v;
        float a = lds_a(As, k, l);
        sfor<16>([&](auto M) {
            constexpr int m = decltype(M)::v;
            C[m] += a * __shfl(Vrow[m], k, 32);
        });
    });
    f16v Pa = (f16v)0.0f, Pb = (f16v)0.0f;
    sfor<16>([&](auto M) {
        constexpr int m = decltype(M)::v;
        float cm = C[m];
        sfor<4>([&](auto J) {
            constexpr int j = decltype(J)::v;
            float4 v  = lds_a4(As, m, j);
            Pa[4*j+0] += cm*v.x;  Pa[4*j+1] += cm*v.y;
            Pa[4*j+2] += cm*v.z;  Pa[4*j+3] += cm*v.w;
            float4 w4 = lds_a4(As, m, j + 4);
            Pb[4*j+0] += cm*w4.x; Pb[4*j+1] += cm*w4.y;
            Pb[4*j+2] += cm*w4.z; Pb[4*j+3] += cm*w4.w;
        });
    });
    constexpr float is = 1.f / kSigma;
    sfor<16>([&](auto N) {
        constexpr int n = decltype(N)::v;
        Pa[n] = (((n      == l) ? 1.f : 0.f) - Pa[n]) * is;
        Pb[n] = (((n + 16 == l) ? 1.f : 0.f) - Pb[n]) * is;
    });
    float d;
    {
        float q = 0.f;
        sfor<16>([&](auto M) {
            constexpr int m = decltype(M)::v;
            q += lds_a(As, m, l) * __shfl(w, m, 32);
        });
        float cval = cg[gs * ND + l];
        float pc0 = 0.f, pc1 = 0.f;
        sfor<16>([&](auto N) {
            constexpr int n = decltype(N)::v;
            pc0 += Pa[n] * __shfl(cval, n,      32);
            pc1 += Pb[n] * __shfl(cval, n + 16, 32);
        });
        d = q - (pc0 + pc1);
    }
    float lb = lbg[gs * ND + l];
    float ub = ubg[gs * ND + l];
    float z  = fminf(fmaxf(0.f, lb), ub);
    float u  = 0.f, x = 0.f;
    for (int it = 0; it < kIters; ++it) {
        Sb[l] = z - u;
        asm volatile("s_waitcnt lgkmcnt(0)" ::: "memory");
        float a0 = d, a1 = 0.f, a2 = 0.f, a3 = 0.f;
        sfor<4>([&](auto K) {
            constexpr int k = decltype(K)::v;
            float4 sA = *reinterpret_cast<const float4*>(&Sb[4*k]);
            float4 sB = *reinterpret_cast<const float4*>(&Sb[4*k + 16]);
            a0 += Pa[4*k+0]*sA.x + Pb[4*k+0]*sB.x;
            a1 += Pa[4*k+1]*sA.y + Pb[4*k+1]*sB.y;
            a2 += Pa[4*k+2]*sA.z + Pb[4*k+2]*sB.z;
            a3 += Pa[4*k+3]*sA.w + Pb[4*k+3]*sB.w;
        });
        x = (a0 + a1) + (a2 + a3);
        float tv = x + u;
        z = fminf(fmaxf(tv, lb), ub);
        u = tv - z;
    }
    outg[gs * ND + l] = x;
}

extern "C" void kernel_launch(void* const* d_in, const int* in_sizes, int n_in,
                              void* d_out, int out_size, void* d_ws, size_t ws_size,
                              hipStream_t stream) {
    const float* A  = (const float*)d_in[0];
    const float* b  = (const float*)d_in[1];
    const float* c  = (const float*)d_in[2];
    const float* lb = (const float*)d_in[3];
    const float* ub = (const float*)d_in[4];
    float* out = (float*)d_out;
    const int B = in_sizes[1] / MD;                       // 32768 samples
    const size_t needP = (size_t)B * ND * ND * sizeof(float);   // 128 MiB
    const size_t needD = (size_t)B * ND * sizeof(float);        // 4 MiB
    if (ws_size >= needP + needD) {
        float* Pws = (float*)d_ws;
        float* dws = Pws + (size_t)B * ND * ND;
        precompute_kernel<<<B / SPA, 128, 0, stream>>>(A, b, c, Pws, dws);
        admm_iter_kernel<<<B / SPB3, 256, 0, stream>>>(Pws, dws, lb, ub, out);
    } else {
        admm_qp_kernel<<<B / SPB, 256, 0, stream>>>(A, b, c, lb, ub, out);
    }
}